// Round 11
// baseline (153.831 us; speedup 1.0000x reference)
//
#include <hip/hip_runtime.h>
#include <hip/hip_bf16.h>

// SimpleGraphConv (RGCN-mean), fused aggregate-first, rel-split register-gather:
//   out[n] = bias + sum_r ( mean_{e: dst=n, type=r} x[src[e]] ) @ W[r]
//
//   1. split counting-sort pipeline (r10 known-good):
//      memset -> pre(hist+wconv+xconv) -> scan1 -> scan23 -> place
//   2. fused kernel: 4-wave blocks, 16-row tile, rels SPLIT across waves
//      (wave w owns rels {2w,2w+1}) -> 4x wave parallelism for the
//      latency-bound gather; partial acc per wave, conflict-free LDS stash,
//      ONE barrier, reduce, single out write. W read frag-linear from
//      global (L2-resident); no LDS staging of W.

#define C128 128
#define BR 16

typedef __attribute__((ext_vector_type(8))) short short8;
typedef __attribute__((ext_vector_type(4))) float f32x4;

__device__ __forceinline__ float bf16u_f32(unsigned short u) {
    union { unsigned int i; float f; } c;
    c.i = ((unsigned int)u) << 16;
    return c.f;
}

// ------- merged: hist | wconv | xconv (independent work, block-split) -------
// wconv: fragment-linear layout. W[r][k][n] with k = kt*32+cg*8+j, n = nt*16+l16
//   -> pos = ((((r*4+kt)*8+nt)*4+cg)*16 + l16)*8 + j   (shorts)

__global__ __launch_bounds__(256) void pre_kernel(const int* __restrict__ ei,
                                                  const int* __restrict__ et,
                                                  unsigned* __restrict__ cursor,
                                                  const float* __restrict__ W,
                                                  __hip_bfloat16* __restrict__ WbT,
                                                  const float* __restrict__ x,
                                                  __hip_bfloat16* __restrict__ xb,
                                                  int n_edges, int n_nodes,
                                                  int hblk, int wblk, int wtot, int xt8) {
    int bid = blockIdx.x;
    if (bid < hblk) {
        int e = bid * 256 + threadIdx.x;
        if (e < n_edges)
            atomicAdd(&cursor[(size_t)et[e] * n_nodes + ei[n_edges + e]], 1u);
    } else if (bid < hblk + wblk) {
        int i = (bid - hblk) * 256 + threadIdx.x;
        if (i < wtot) {
            int r = i >> 14, k = (i >> 7) & 127, n = i & 127;
            int kt = k >> 5, cg = (k >> 3) & 3, j = k & 7;
            int nt = n >> 4, l16 = n & 15;
            int pos = ((((r * 4 + kt) * 8 + nt) * 4 + cg) * 16 + l16) * 8 + j;
            WbT[pos] = __float2bfloat16(W[i]);
        }
    } else {
        int i = (bid - hblk - wblk) * 256 + threadIdx.x;
        if (i < xt8) {
            const float4* src = reinterpret_cast<const float4*>(x + (size_t)i * 8);
            float4 v0 = src[0], v1 = src[1];
            short8 o;
            o[0] = (short)__bfloat16_as_ushort(__float2bfloat16(v0.x));
            o[1] = (short)__bfloat16_as_ushort(__float2bfloat16(v0.y));
            o[2] = (short)__bfloat16_as_ushort(__float2bfloat16(v0.z));
            o[3] = (short)__bfloat16_as_ushort(__float2bfloat16(v0.w));
            o[4] = (short)__bfloat16_as_ushort(__float2bfloat16(v1.x));
            o[5] = (short)__bfloat16_as_ushort(__float2bfloat16(v1.y));
            o[6] = (short)__bfloat16_as_ushort(__float2bfloat16(v1.z));
            o[7] = (short)__bfloat16_as_ushort(__float2bfloat16(v1.w));
            *reinterpret_cast<short8*>(reinterpret_cast<unsigned short*>(xb) + (size_t)i * 8) = o;
        }
    }
}

// ---------------- scan: scan1 + merged scan23 ----------------

__global__ __launch_bounds__(256) void scan1_kernel(const unsigned* __restrict__ cnt,
                                                    unsigned* __restrict__ part, int total) {
    __shared__ unsigned s[256];
    int t = threadIdx.x;
    int base = blockIdx.x * 1024 + t * 4;
    unsigned sum = 0;
#pragma unroll
    for (int i = 0; i < 4; ++i) {
        int idx = base + i;
        if (idx < total) sum += cnt[idx];
    }
    s[t] = sum;
    __syncthreads();
    for (int d = 128; d > 0; d >>= 1) {
        if (t < d) s[t] += s[t + d];
        __syncthreads();
    }
    if (t == 0) part[blockIdx.x] = s[0];
}

__global__ __launch_bounds__(256) void scan23_kernel(unsigned* __restrict__ cursor,
                                                     unsigned* __restrict__ off,
                                                     const unsigned* __restrict__ part,
                                                     int total, int n_edges) {
    __shared__ unsigned s[256];
    const int t = threadIdx.x;
    const int bid = blockIdx.x;

    unsigned basesum = 0;
    for (int i0 = 0; i0 < bid; i0 += 256) {
        int i = i0 + t;
        s[t] = (i < bid) ? part[i] : 0u;
        __syncthreads();
        for (int d = 128; d > 0; d >>= 1) {
            if (t < d) s[t] += s[t + d];
            __syncthreads();
        }
        basesum += s[0];
        __syncthreads();
    }

    int base = bid * 1024 + t * 4;
    unsigned v[4];
    unsigned tsum = 0;
#pragma unroll
    for (int i = 0; i < 4; ++i) {
        int idx = base + i;
        v[i] = (idx < total) ? cursor[idx] : 0u;
        tsum += v[i];
    }
    s[t] = tsum;
    __syncthreads();
    for (int d = 1; d < 256; d <<= 1) {
        unsigned u = (t >= d) ? s[t - d] : 0u;
        __syncthreads();
        s[t] += u;
        __syncthreads();
    }
    unsigned run = s[t] - tsum + basesum;
#pragma unroll
    for (int i = 0; i < 4; ++i) {
        int idx = base + i;
        if (idx < total) {
            off[idx] = run;
            cursor[idx] = run;
            run += v[i];
        }
    }
    if (bid == 0 && t == 0) off[total] = (unsigned)n_edges;
}

__global__ __launch_bounds__(256) void place_kernel(const int* __restrict__ ei,
                                                    const int* __restrict__ et,
                                                    unsigned* __restrict__ cursor,
                                                    int* __restrict__ sorted_src,
                                                    int n_edges, int n_nodes) {
    int e = blockIdx.x * 256 + threadIdx.x;
    if (e < n_edges) {
        int src = ei[e];
        int dst = ei[n_edges + e];
        int key = et[e] * n_nodes + dst;
        unsigned pos = atomicAdd(&cursor[key], 1u);
        sorted_src[pos] = src;
    }
}

// ------- fused: 4-wave blocks, rels split across waves, one barrier -------

__global__ __launch_bounds__(256, 4) void fused_kernel(
    const __hip_bfloat16* __restrict__ xb, const int* __restrict__ ss,
    const unsigned* __restrict__ off, const __hip_bfloat16* __restrict__ WbT,
    const float* __restrict__ bias, float* __restrict__ out,
    int n_nodes, int n_rel) {
    __shared__ __align__(16) f32x4 sred[8][256];   // [nt][w*64+lane], 32 KB
    const int t = threadIdx.x, lane = t & 63, w = t >> 6;
    const int l16 = lane & 15, cg = lane >> 4;
    const int row0 = blockIdx.x * BR;
    const int node = row0 + l16;          // row owned by 4 cg-lanes
    const bool live = (node < n_nodes);
    const unsigned short* xbu = reinterpret_cast<const unsigned short*>(xb);
    const unsigned short* wpu = reinterpret_cast<const unsigned short*>(WbT);

    f32x4 acc[8];
#pragma unroll
    for (int i = 0; i < 8; ++i) acc[i] = (f32x4){0.f, 0.f, 0.f, 0.f};

    const int p_end = (w * 2 + 2 < n_rel) ? (w * 2 + 2) : n_rel;
    for (int p = w * 2; p < p_end; ++p) {
        unsigned b = 0, e = 0;
        if (live) {
            size_t k = (size_t)p * n_nodes + node;
            b = off[k];
            e = off[k + 1];
        }

        // register gather: lane accumulates its 4x8 A-fragment elements
        float a[4][8];
#pragma unroll
        for (int kt = 0; kt < 4; ++kt)
#pragma unroll
            for (int j = 0; j < 8; ++j) a[kt][j] = 0.f;

        int n0 = (int)(e - b);
        int eb = (int)b;
        int s0 = (n0 > 0) ? ss[eb] : 0;
        for (int i = 0; i < n0; ++i) {
            int sv = s0;
            s0 = (i + 1 < n0) ? ss[eb + i + 1] : 0;  // prefetch next src
            const unsigned short* rp = xbu + ((size_t)sv << 7) + cg * 8;
            short8 v0 = *reinterpret_cast<const short8*>(rp);
            short8 v1 = *reinterpret_cast<const short8*>(rp + 32);
            short8 v2 = *reinterpret_cast<const short8*>(rp + 64);
            short8 v3 = *reinterpret_cast<const short8*>(rp + 96);
#pragma unroll
            for (int j = 0; j < 8; ++j) {
                a[0][j] += bf16u_f32((unsigned short)v0[j]);
                a[1][j] += bf16u_f32((unsigned short)v1[j]);
                a[2][j] += bf16u_f32((unsigned short)v2[j]);
                a[3][j] += bf16u_f32((unsigned short)v3[j]);
            }
        }
        float inv = (n0 > 0) ? 1.0f / (float)n0 : 0.0f;
        short8 af[4];
#pragma unroll
        for (int kt = 0; kt < 4; ++kt) {
            short8 o;
#pragma unroll
            for (int j = 0; j < 8; ++j)
                o[j] = (short)__bfloat16_as_ushort(__float2bfloat16(a[kt][j] * inv));
            af[kt] = o;
        }

        // B-fragments straight from global (frag-linear, coalesced 1KB/wave reads)
#pragma unroll
        for (int kt = 0; kt < 4; ++kt) {
            short8 bf[8];
#pragma unroll
            for (int nt = 0; nt < 8; ++nt)
                bf[nt] = *reinterpret_cast<const short8*>(
                    wpu + ((size_t)(((p * 4 + kt) * 8 + nt) * 64 + lane)) * 8);
#pragma unroll
            for (int nt = 0; nt < 8; ++nt)
                acc[nt] = __builtin_amdgcn_mfma_f32_16x16x32_bf16(af[kt], bf[nt],
                                                                  acc[nt], 0, 0, 0);
        }
    }

    // stash partials (16B lane stride -> conflict-free), reduce across waves
#pragma unroll
    for (int nt = 0; nt < 8; ++nt) sred[nt][t] = acc[nt];
    __syncthreads();

#pragma unroll
    for (int q = 0; q < 2; ++q) {
        int nt = w * 2 + q;
        f32x4 r = sred[nt][lane];
        r += sred[nt][64 + lane];
        r += sred[nt][128 + lane];
        r += sred[nt][192 + lane];
        int col = nt * 16 + l16;
        float bv = bias[col];
#pragma unroll
        for (int i = 0; i < 4; ++i) {
            int rrow = row0 + (cg << 2) + i;
            if (rrow < n_nodes)
                out[(size_t)rrow * C128 + col] = r[i] + bv;
        }
    }
}

// ---------------- host ----------------

static inline char* align16p(char* p) {
    return (char*)(((uintptr_t)p + 15) & ~(uintptr_t)15);
}

extern "C" void kernel_launch(void* const* d_in, const int* in_sizes, int n_in,
                              void* d_out, int out_size, void* d_ws, size_t ws_size,
                              hipStream_t stream) {
    const float* x    = (const float*)d_in[0];
    const int*   ei   = (const int*)d_in[1];   // [2][E]
    const int*   et   = (const int*)d_in[2];   // [E]
    const float* W    = (const float*)d_in[3]; // [R][128][128]
    const float* bias = (const float*)d_in[4]; // [128]
    float* out = (float*)d_out;

    const int n_nodes = in_sizes[0] / C128;
    const int n_edges = in_sizes[2];
    const int n_rel   = in_sizes[3] / (C128 * C128);
    const int RN = n_rel * n_nodes;

    // workspace: off | cursor | part | sorted_src | WbT | xb   (~19 MB)
    char* p = (char*)d_ws;
    unsigned* off = (unsigned*)p;      p += (size_t)(RN + 1) * 4; p = align16p(p);
    unsigned* cursor = (unsigned*)p;   p += (size_t)RN * 4;       p = align16p(p);
    unsigned* part = (unsigned*)p;     p += 4096 * 4;
    int* sorted_src = (int*)p;         p += (size_t)n_edges * 4;  p = align16p(p);
    __hip_bfloat16* WbT = (__hip_bfloat16*)p; p += (size_t)n_rel * C128 * C128 * 2; p = align16p(p);
    __hip_bfloat16* xb = (__hip_bfloat16*)p;

    hipMemsetAsync(cursor, 0, (size_t)RN * 4, stream);

    // hist + wconv + xconv in one launch (right-sized grid, block-range split)
    int wtot = n_rel * C128 * C128;
    int xt8 = n_nodes * (C128 / 8);
    int hblk = (n_edges + 255) / 256;
    int wblk = (wtot + 255) / 256;
    int xblk = (xt8 + 255) / 256;
    pre_kernel<<<hblk + wblk + xblk, 256, 0, stream>>>(ei, et, cursor, W, WbT, x, xb,
                                                       n_edges, n_nodes, hblk, wblk, wtot, xt8);

    int nblk = (RN + 1023) / 1024;
    scan1_kernel<<<nblk, 256, 0, stream>>>(cursor, part, RN);
    scan23_kernel<<<nblk, 256, 0, stream>>>(cursor, off, part, RN, n_edges);
    place_kernel<<<(n_edges + 255) / 256, 256, 0, stream>>>(ei, et, cursor, sorted_src,
                                                            n_edges, n_nodes);

    int mblk = (n_nodes + BR - 1) / BR;
    fused_kernel<<<mblk, 256, 0, stream>>>(xb, sorted_src, off, WbT, bias, out,
                                           n_nodes, n_rel);
}

// Round 12
// 123.975 us; speedup vs baseline: 1.2408x; 1.2408x over previous
//
#include <hip/hip_runtime.h>
#include <hip/hip_bf16.h>

// SimpleGraphConv (RGCN-mean), fused aggregate-first, barrier-free register-gather:
//   out[n] = bias + sum_r ( mean_{e: dst=n, type=r} x[src[e]] ) @ W[r]
//
//   1. counting-sort pipeline, rank-trick (no atomics in place):
//      memset -> pre(hist+rank+wconv+xconv) -> scan1 -> scan23 -> place
//      hist's atomicAdd old-value IS the edge's rank within its key run.
//   2. fused kernel (r10 verbatim): 1-wave blocks (16 rows), no LDS, no barriers:
//      - W frag-linear [r][kt][nt][lane][16B]: coalesced 1KB wave reads, L2-res
//      - lane gathers its MFMA A-fragment in f32 regs over the row's CSR run
//      - acc across rels; out written once. At the ~1.65 TB/s random-access
//        BW wall (r10/r11 probes) -> structural floor ~70 us.

#define C128 128
#define BR 16

typedef __attribute__((ext_vector_type(8))) short short8;
typedef __attribute__((ext_vector_type(4))) float f32x4;

__device__ __forceinline__ float bf16u_f32(unsigned short u) {
    union { unsigned int i; float f; } c;
    c.i = ((unsigned int)u) << 16;
    return c.f;
}

// ------- merged: hist(+rank) | wconv | xconv (block-range split) -------
// wconv: fragment-linear. W[r][k][n], k=kt*32+cg*8+j, n=nt*16+l16
//   -> pos = ((((r*4+kt)*8+nt)*4+cg)*16 + l16)*8 + j   (shorts)

__global__ __launch_bounds__(256) void pre_kernel(const int* __restrict__ ei,
                                                  const int* __restrict__ et,
                                                  unsigned* __restrict__ cursor,
                                                  unsigned* __restrict__ rank,
                                                  const float* __restrict__ W,
                                                  __hip_bfloat16* __restrict__ WbT,
                                                  const float* __restrict__ x,
                                                  __hip_bfloat16* __restrict__ xb,
                                                  int n_edges, int n_nodes,
                                                  int hblk, int wblk, int wtot, int xt8) {
    int bid = blockIdx.x;
    if (bid < hblk) {
        int e = bid * 256 + threadIdx.x;
        if (e < n_edges) {
            unsigned key = (unsigned)et[e] * (unsigned)n_nodes + (unsigned)ei[n_edges + e];
            rank[e] = atomicAdd(&cursor[key], 1u);   // old count = rank within run
        }
    } else if (bid < hblk + wblk) {
        int i = (bid - hblk) * 256 + threadIdx.x;
        if (i < wtot) {
            int r = i >> 14, k = (i >> 7) & 127, n = i & 127;
            int kt = k >> 5, cg = (k >> 3) & 3, j = k & 7;
            int nt = n >> 4, l16 = n & 15;
            int pos = ((((r * 4 + kt) * 8 + nt) * 4 + cg) * 16 + l16) * 8 + j;
            WbT[pos] = __float2bfloat16(W[i]);
        }
    } else {
        int i = (bid - hblk - wblk) * 256 + threadIdx.x;
        if (i < xt8) {
            const float4* src = reinterpret_cast<const float4*>(x + (size_t)i * 8);
            float4 v0 = src[0], v1 = src[1];
            short8 o;
            o[0] = (short)__bfloat16_as_ushort(__float2bfloat16(v0.x));
            o[1] = (short)__bfloat16_as_ushort(__float2bfloat16(v0.y));
            o[2] = (short)__bfloat16_as_ushort(__float2bfloat16(v0.z));
            o[3] = (short)__bfloat16_as_ushort(__float2bfloat16(v0.w));
            o[4] = (short)__bfloat16_as_ushort(__float2bfloat16(v1.x));
            o[5] = (short)__bfloat16_as_ushort(__float2bfloat16(v1.y));
            o[6] = (short)__bfloat16_as_ushort(__float2bfloat16(v1.z));
            o[7] = (short)__bfloat16_as_ushort(__float2bfloat16(v1.w));
            *reinterpret_cast<short8*>(reinterpret_cast<unsigned short*>(xb) + (size_t)i * 8) = o;
        }
    }
}

// ---------------- scan: scan1 + merged scan23 ----------------

__global__ __launch_bounds__(256) void scan1_kernel(const unsigned* __restrict__ cnt,
                                                    unsigned* __restrict__ part, int total) {
    __shared__ unsigned s[256];
    int t = threadIdx.x;
    int base = blockIdx.x * 1024 + t * 4;
    unsigned sum = 0;
#pragma unroll
    for (int i = 0; i < 4; ++i) {
        int idx = base + i;
        if (idx < total) sum += cnt[idx];
    }
    s[t] = sum;
    __syncthreads();
    for (int d = 128; d > 0; d >>= 1) {
        if (t < d) s[t] += s[t + d];
        __syncthreads();
    }
    if (t == 0) part[blockIdx.x] = s[0];
}

// each block reduces part[0..bid) itself, then scans its 1024 keys -> off
__global__ __launch_bounds__(256) void scan23_kernel(const unsigned* __restrict__ cursor,
                                                     unsigned* __restrict__ off,
                                                     const unsigned* __restrict__ part,
                                                     int total, int n_edges) {
    __shared__ unsigned s[256];
    const int t = threadIdx.x;
    const int bid = blockIdx.x;

    unsigned basesum = 0;
    for (int i0 = 0; i0 < bid; i0 += 256) {
        int i = i0 + t;
        s[t] = (i < bid) ? part[i] : 0u;
        __syncthreads();
        for (int d = 128; d > 0; d >>= 1) {
            if (t < d) s[t] += s[t + d];
            __syncthreads();
        }
        basesum += s[0];
        __syncthreads();
    }

    int base = bid * 1024 + t * 4;
    unsigned v[4];
    unsigned tsum = 0;
#pragma unroll
    for (int i = 0; i < 4; ++i) {
        int idx = base + i;
        v[i] = (idx < total) ? cursor[idx] : 0u;
        tsum += v[i];
    }
    s[t] = tsum;
    __syncthreads();
    for (int d = 1; d < 256; d <<= 1) {
        unsigned u = (t >= d) ? s[t - d] : 0u;
        __syncthreads();
        s[t] += u;
        __syncthreads();
    }
    unsigned run = s[t] - tsum + basesum;
#pragma unroll
    for (int i = 0; i < 4; ++i) {
        int idx = base + i;
        if (idx < total) {
            off[idx] = run;
            run += v[i];
        }
    }
    if (bid == 0 && t == 0) off[total] = (unsigned)n_edges;
}

// ------- place: atomic-free, pos = off[key] + rank[e] -------

__global__ __launch_bounds__(256) void place_kernel(const int* __restrict__ ei,
                                                    const int* __restrict__ et,
                                                    const unsigned* __restrict__ off,
                                                    const unsigned* __restrict__ rank,
                                                    int* __restrict__ sorted_src,
                                                    int n_edges, int n_nodes) {
    int e = blockIdx.x * 256 + threadIdx.x;
    if (e < n_edges) {
        unsigned key = (unsigned)et[e] * (unsigned)n_nodes + (unsigned)ei[n_edges + e];
        unsigned pos = off[key] + rank[e];
        sorted_src[pos] = ei[e];
    }
}

// ---------------- fused: 1-wave blocks, no LDS, no barriers (r10) ----------------

__global__ __launch_bounds__(64, 3) void fused_kernel(
    const __hip_bfloat16* __restrict__ xb, const int* __restrict__ ss,
    const unsigned* __restrict__ off, const __hip_bfloat16* __restrict__ WbT,
    const float* __restrict__ bias, float* __restrict__ out,
    int n_nodes, int n_rel) {
    const int lane = threadIdx.x & 63;
    const int l16 = lane & 15, cg = lane >> 4;
    const int row0 = blockIdx.x * BR;
    const int node = row0 + l16;          // row owned by 4 cg-lanes
    const bool live = (node < n_nodes);
    const unsigned short* xbu = reinterpret_cast<const unsigned short*>(xb);
    const unsigned short* wpu = reinterpret_cast<const unsigned short*>(WbT);

    f32x4 acc[8];
#pragma unroll
    for (int i = 0; i < 8; ++i) acc[i] = (f32x4){0.f, 0.f, 0.f, 0.f};

    unsigned b = 0, e = 0;
    if (live) { b = off[node]; e = off[node + 1]; }   // rel 0 key = node

    for (int p = 0; p < n_rel; ++p) {
        // depth-1 prefetch of next rel's CSR bounds
        unsigned nb = 0, ne = 0;
        if (p + 1 < n_rel && live) {
            size_t k = (size_t)(p + 1) * n_nodes + node;
            nb = off[k];
            ne = off[k + 1];
        }

        // register gather: lane accumulates its 4x8 A-fragment elements
        float a[4][8];
#pragma unroll
        for (int kt = 0; kt < 4; ++kt)
#pragma unroll
            for (int j = 0; j < 8; ++j) a[kt][j] = 0.f;

        int n0 = (int)(e - b);
        int eb = (int)b;
        int s0 = (n0 > 0) ? ss[eb] : 0;
        for (int i = 0; i < n0; ++i) {
            int sv = s0;
            s0 = (i + 1 < n0) ? ss[eb + i + 1] : 0;  // prefetch next src
            const unsigned short* rp = xbu + ((size_t)sv << 7) + cg * 8;
            short8 v0 = *reinterpret_cast<const short8*>(rp);
            short8 v1 = *reinterpret_cast<const short8*>(rp + 32);
            short8 v2 = *reinterpret_cast<const short8*>(rp + 64);
            short8 v3 = *reinterpret_cast<const short8*>(rp + 96);
#pragma unroll
            for (int j = 0; j < 8; ++j) {
                a[0][j] += bf16u_f32((unsigned short)v0[j]);
                a[1][j] += bf16u_f32((unsigned short)v1[j]);
                a[2][j] += bf16u_f32((unsigned short)v2[j]);
                a[3][j] += bf16u_f32((unsigned short)v3[j]);
            }
        }
        float inv = (n0 > 0) ? 1.0f / (float)n0 : 0.0f;
        short8 af[4];
#pragma unroll
        for (int kt = 0; kt < 4; ++kt) {
            short8 o;
#pragma unroll
            for (int j = 0; j < 8; ++j)
                o[j] = (short)__bfloat16_as_ushort(__float2bfloat16(a[kt][j] * inv));
            af[kt] = o;
        }

        // B-fragments straight from global (frag-linear, coalesced 1KB/wave reads)
#pragma unroll
        for (int kt = 0; kt < 4; ++kt) {
            short8 bf[8];
#pragma unroll
            for (int nt = 0; nt < 8; ++nt)
                bf[nt] = *reinterpret_cast<const short8*>(
                    wpu + ((size_t)(((p * 4 + kt) * 8 + nt) * 64 + lane)) * 8);
#pragma unroll
            for (int nt = 0; nt < 8; ++nt)
                acc[nt] = __builtin_amdgcn_mfma_f32_16x16x32_bf16(af[kt], bf[nt],
                                                                  acc[nt], 0, 0, 0);
        }

        b = nb;
        e = ne;
    }

    // epilogue: D row = 4*cg+i, col = nt*16+l16
    const int rbase = row0 + (cg << 2);
#pragma unroll
    for (int nt = 0; nt < 8; ++nt) {
        int col = nt * 16 + l16;
        float bv = bias[col];
#pragma unroll
        for (int i = 0; i < 4; ++i) {
            int r = rbase + i;
            if (r < n_nodes)
                out[(size_t)r * C128 + col] = acc[nt][i] + bv;
        }
    }
}

// ---------------- host ----------------

static inline char* align16p(char* p) {
    return (char*)(((uintptr_t)p + 15) & ~(uintptr_t)15);
}

extern "C" void kernel_launch(void* const* d_in, const int* in_sizes, int n_in,
                              void* d_out, int out_size, void* d_ws, size_t ws_size,
                              hipStream_t stream) {
    const float* x    = (const float*)d_in[0];
    const int*   ei   = (const int*)d_in[1];   // [2][E]
    const int*   et   = (const int*)d_in[2];   // [E]
    const float* W    = (const float*)d_in[3]; // [R][128][128]
    const float* bias = (const float*)d_in[4]; // [128]
    float* out = (float*)d_out;

    const int n_nodes = in_sizes[0] / C128;
    const int n_edges = in_sizes[2];
    const int n_rel   = in_sizes[3] / (C128 * C128);
    const int RN = n_rel * n_nodes;

    // workspace: off | cursor | part | rank | sorted_src | WbT | xb   (~21 MB)
    char* p = (char*)d_ws;
    unsigned* off = (unsigned*)p;      p += (size_t)(RN + 1) * 4; p = align16p(p);
    unsigned* cursor = (unsigned*)p;   p += (size_t)RN * 4;       p = align16p(p);
    unsigned* part = (unsigned*)p;     p += 4096 * 4;
    unsigned* rank = (unsigned*)p;     p += (size_t)n_edges * 4;  p = align16p(p);
    int* sorted_src = (int*)p;         p += (size_t)n_edges * 4;  p = align16p(p);
    __hip_bfloat16* WbT = (__hip_bfloat16*)p; p += (size_t)n_rel * C128 * C128 * 2; p = align16p(p);
    __hip_bfloat16* xb = (__hip_bfloat16*)p;

    hipMemsetAsync(cursor, 0, (size_t)RN * 4, stream);

    // hist(+rank) + wconv + xconv in one launch (right-sized, block-range split)
    int wtot = n_rel * C128 * C128;
    int xt8 = n_nodes * (C128 / 8);
    int hblk = (n_edges + 255) / 256;
    int wblk = (wtot + 255) / 256;
    int xblk = (xt8 + 255) / 256;
    pre_kernel<<<hblk + wblk + xblk, 256, 0, stream>>>(ei, et, cursor, rank, W, WbT, x, xb,
                                                       n_edges, n_nodes, hblk, wblk, wtot, xt8);

    int nblk = (RN + 1023) / 1024;
    scan1_kernel<<<nblk, 256, 0, stream>>>(cursor, part, RN);
    scan23_kernel<<<nblk, 256, 0, stream>>>(cursor, off, part, RN, n_edges);
    place_kernel<<<(n_edges + 255) / 256, 256, 0, stream>>>(ei, et, off, rank, sorted_src,
                                                            n_edges, n_nodes);

    int mblk = (n_nodes + BR - 1) / BR;
    fused_kernel<<<mblk, 64, 0, stream>>>(xb, sorted_src, off, WbT, bias, out,
                                          n_nodes, n_rel);
}

// Round 13
// 123.277 us; speedup vs baseline: 1.2478x; 1.0057x over previous
//
#include <hip/hip_runtime.h>
#include <hip/hip_bf16.h>

// SimpleGraphConv (RGCN-mean), fused aggregate-first, barrier-free register-gather:
//   out[n] = bias + sum_r ( mean_{e: dst=n, type=r} x[src[e]] ) @ W[r]
//
//   1. counting-sort pipeline, rank-trick (no atomics in place), 4 edges/thread:
//      memset -> pre(hist+rank | wconv | xconv) -> scan1 -> scan23 -> place
//   2. fused kernel: 1-wave blocks (16 rows), no LDS, no barriers:
//      - W frag-linear [r][kt][nt][lane][16B]: coalesced 1KB wave reads, L2-res
//      - lane gathers its MFMA A-fragment in f32 regs over the row's CSR run;
//        bf16->f32 via u32 bit-ops (2 elems per 2 VALU ops)
//      - acc across rels; out written once. At the ~1.6 TB/s random-gather
//        wall (r10/r11 probes) -> structural floor ~65-70 us.

#define C128 128
#define BR 16

typedef __attribute__((ext_vector_type(8))) short short8;
typedef __attribute__((ext_vector_type(4))) float f32x4;

__device__ __forceinline__ float asf(unsigned u) { return __uint_as_float(u); }

// ------- merged: hist(+rank) | wconv | xconv (block-range split) -------
// wconv: fragment-linear. W[r][k][n], k=kt*32+cg*8+j, n=nt*16+l16
//   -> pos = ((((r*4+kt)*8+nt)*4+cg)*16 + l16)*8 + j   (shorts)

__global__ __launch_bounds__(256) void pre_kernel(const int* __restrict__ ei,
                                                  const int* __restrict__ et,
                                                  unsigned* __restrict__ cursor,
                                                  unsigned* __restrict__ rank,
                                                  const float* __restrict__ W,
                                                  __hip_bfloat16* __restrict__ WbT,
                                                  const float* __restrict__ x,
                                                  __hip_bfloat16* __restrict__ xb,
                                                  int n_edges, int n_nodes,
                                                  int hblk, int wblk, int wtot, int xt8) {
    int bid = blockIdx.x;
    if (bid < hblk) {
        int e0 = (bid * 256 + threadIdx.x) * 4;
        if (e0 + 3 < n_edges) {
            int4 t4 = *reinterpret_cast<const int4*>(et + e0);
            int4 d4 = *reinterpret_cast<const int4*>(ei + n_edges + e0);
            uint4 r4;
            r4.x = atomicAdd(&cursor[(unsigned)t4.x * (unsigned)n_nodes + (unsigned)d4.x], 1u);
            r4.y = atomicAdd(&cursor[(unsigned)t4.y * (unsigned)n_nodes + (unsigned)d4.y], 1u);
            r4.z = atomicAdd(&cursor[(unsigned)t4.z * (unsigned)n_nodes + (unsigned)d4.z], 1u);
            r4.w = atomicAdd(&cursor[(unsigned)t4.w * (unsigned)n_nodes + (unsigned)d4.w], 1u);
            *reinterpret_cast<uint4*>(rank + e0) = r4;
        } else {
            for (int e = e0; e < n_edges && e < e0 + 4; ++e) {
                unsigned key = (unsigned)et[e] * (unsigned)n_nodes + (unsigned)ei[n_edges + e];
                rank[e] = atomicAdd(&cursor[key], 1u);
            }
        }
    } else if (bid < hblk + wblk) {
        int i = (bid - hblk) * 256 + threadIdx.x;
        if (i < wtot) {
            int r = i >> 14, k = (i >> 7) & 127, n = i & 127;
            int kt = k >> 5, cg = (k >> 3) & 3, j = k & 7;
            int nt = n >> 4, l16 = n & 15;
            int pos = ((((r * 4 + kt) * 8 + nt) * 4 + cg) * 16 + l16) * 8 + j;
            WbT[pos] = __float2bfloat16(W[i]);
        }
    } else {
        int i = (bid - hblk - wblk) * 256 + threadIdx.x;
        if (i < xt8) {
            const float4* src = reinterpret_cast<const float4*>(x + (size_t)i * 8);
            float4 v0 = src[0], v1 = src[1];
            short8 o;
            o[0] = (short)__bfloat16_as_ushort(__float2bfloat16(v0.x));
            o[1] = (short)__bfloat16_as_ushort(__float2bfloat16(v0.y));
            o[2] = (short)__bfloat16_as_ushort(__float2bfloat16(v0.z));
            o[3] = (short)__bfloat16_as_ushort(__float2bfloat16(v0.w));
            o[4] = (short)__bfloat16_as_ushort(__float2bfloat16(v1.x));
            o[5] = (short)__bfloat16_as_ushort(__float2bfloat16(v1.y));
            o[6] = (short)__bfloat16_as_ushort(__float2bfloat16(v1.z));
            o[7] = (short)__bfloat16_as_ushort(__float2bfloat16(v1.w));
            *reinterpret_cast<short8*>(reinterpret_cast<unsigned short*>(xb) + (size_t)i * 8) = o;
        }
    }
}

// ---------------- scan: scan1 + merged scan23 ----------------

__global__ __launch_bounds__(256) void scan1_kernel(const unsigned* __restrict__ cnt,
                                                    unsigned* __restrict__ part, int total) {
    __shared__ unsigned s[256];
    int t = threadIdx.x;
    int base = blockIdx.x * 1024 + t * 4;
    unsigned sum = 0;
#pragma unroll
    for (int i = 0; i < 4; ++i) {
        int idx = base + i;
        if (idx < total) sum += cnt[idx];
    }
    s[t] = sum;
    __syncthreads();
    for (int d = 128; d > 0; d >>= 1) {
        if (t < d) s[t] += s[t + d];
        __syncthreads();
    }
    if (t == 0) part[blockIdx.x] = s[0];
}

// each block reduces part[0..bid) itself, then scans its 1024 keys -> off
__global__ __launch_bounds__(256) void scan23_kernel(const unsigned* __restrict__ cursor,
                                                     unsigned* __restrict__ off,
                                                     const unsigned* __restrict__ part,
                                                     int total, int n_edges) {
    __shared__ unsigned s[256];
    const int t = threadIdx.x;
    const int bid = blockIdx.x;

    unsigned basesum = 0;
    for (int i0 = 0; i0 < bid; i0 += 256) {
        int i = i0 + t;
        s[t] = (i < bid) ? part[i] : 0u;
        __syncthreads();
        for (int d = 128; d > 0; d >>= 1) {
            if (t < d) s[t] += s[t + d];
            __syncthreads();
        }
        basesum += s[0];
        __syncthreads();
    }

    int base = bid * 1024 + t * 4;
    unsigned v[4];
    unsigned tsum = 0;
#pragma unroll
    for (int i = 0; i < 4; ++i) {
        int idx = base + i;
        v[i] = (idx < total) ? cursor[idx] : 0u;
        tsum += v[i];
    }
    s[t] = tsum;
    __syncthreads();
    for (int d = 1; d < 256; d <<= 1) {
        unsigned u = (t >= d) ? s[t - d] : 0u;
        __syncthreads();
        s[t] += u;
        __syncthreads();
    }
    unsigned run = s[t] - tsum + basesum;
#pragma unroll
    for (int i = 0; i < 4; ++i) {
        int idx = base + i;
        if (idx < total) {
            off[idx] = run;
            run += v[i];
        }
    }
    if (bid == 0 && t == 0) off[total] = (unsigned)n_edges;
}

// ------- place: atomic-free, pos = off[key] + rank[e], 4 edges/thread -------

__global__ __launch_bounds__(256) void place_kernel(const int* __restrict__ ei,
                                                    const int* __restrict__ et,
                                                    const unsigned* __restrict__ off,
                                                    const unsigned* __restrict__ rank,
                                                    int* __restrict__ sorted_src,
                                                    int n_edges, int n_nodes) {
    int e0 = (blockIdx.x * 256 + threadIdx.x) * 4;
    if (e0 + 3 < n_edges) {
        int4 t4 = *reinterpret_cast<const int4*>(et + e0);
        int4 d4 = *reinterpret_cast<const int4*>(ei + n_edges + e0);
        int4 s4 = *reinterpret_cast<const int4*>(ei + e0);
        uint4 r4 = *reinterpret_cast<const uint4*>(rank + e0);
        unsigned p0 = off[(unsigned)t4.x * (unsigned)n_nodes + (unsigned)d4.x] + r4.x;
        unsigned p1 = off[(unsigned)t4.y * (unsigned)n_nodes + (unsigned)d4.y] + r4.y;
        unsigned p2 = off[(unsigned)t4.z * (unsigned)n_nodes + (unsigned)d4.z] + r4.z;
        unsigned p3 = off[(unsigned)t4.w * (unsigned)n_nodes + (unsigned)d4.w] + r4.w;
        sorted_src[p0] = s4.x;
        sorted_src[p1] = s4.y;
        sorted_src[p2] = s4.z;
        sorted_src[p3] = s4.w;
    } else {
        for (int e = e0; e < n_edges && e < e0 + 4; ++e) {
            unsigned key = (unsigned)et[e] * (unsigned)n_nodes + (unsigned)ei[n_edges + e];
            sorted_src[off[key] + rank[e]] = ei[e];
        }
    }
}

// ---------------- fused: 1-wave blocks, no LDS, no barriers ----------------

__global__ __launch_bounds__(64, 3) void fused_kernel(
    const __hip_bfloat16* __restrict__ xb, const int* __restrict__ ss,
    const unsigned* __restrict__ off, const __hip_bfloat16* __restrict__ WbT,
    const float* __restrict__ bias, float* __restrict__ out,
    int n_nodes, int n_rel) {
    const int lane = threadIdx.x & 63;
    const int l16 = lane & 15, cg = lane >> 4;
    const int row0 = blockIdx.x * BR;
    const int node = row0 + l16;          // row owned by 4 cg-lanes
    const bool live = (node < n_nodes);
    const unsigned* xbu32 = reinterpret_cast<const unsigned*>(xb);
    const unsigned short* wpu = reinterpret_cast<const unsigned short*>(WbT);

    f32x4 acc[8];
#pragma unroll
    for (int i = 0; i < 8; ++i) acc[i] = (f32x4){0.f, 0.f, 0.f, 0.f};

    unsigned b = 0, e = 0;
    if (live) { b = off[node]; e = off[node + 1]; }   // rel 0 key = node

// accumulate 8 channels (4 u32 = 8 bf16) into a[KT][0..7]
#define ACC8(KT, U)                                               \
    a[KT][0] += asf(U.x << 16); a[KT][1] += asf(U.x & 0xFFFF0000u); \
    a[KT][2] += asf(U.y << 16); a[KT][3] += asf(U.y & 0xFFFF0000u); \
    a[KT][4] += asf(U.z << 16); a[KT][5] += asf(U.z & 0xFFFF0000u); \
    a[KT][6] += asf(U.w << 16); a[KT][7] += asf(U.w & 0xFFFF0000u);

    for (int p = 0; p < n_rel; ++p) {
        // depth-1 prefetch of next rel's CSR bounds
        unsigned nb = 0, ne = 0;
        if (p + 1 < n_rel && live) {
            size_t k = (size_t)(p + 1) * n_nodes + node;
            nb = off[k];
            ne = off[k + 1];
        }

        // register gather: lane accumulates its 4x8 A-fragment elements
        float a[4][8];
#pragma unroll
        for (int kt = 0; kt < 4; ++kt)
#pragma unroll
            for (int j = 0; j < 8; ++j) a[kt][j] = 0.f;

        int n0 = (int)(e - b);
        int eb = (int)b;
        int s0 = (n0 > 0) ? ss[eb] : 0;
        for (int i = 0; i < n0; ++i) {
            int sv = s0;
            s0 = (i + 1 < n0) ? ss[eb + i + 1] : 0;  // prefetch next src
            const unsigned* rp = xbu32 + ((size_t)sv << 6) + cg * 4;
            uint4 u0 = *reinterpret_cast<const uint4*>(rp);
            uint4 u1 = *reinterpret_cast<const uint4*>(rp + 16);
            uint4 u2 = *reinterpret_cast<const uint4*>(rp + 32);
            uint4 u3 = *reinterpret_cast<const uint4*>(rp + 48);
            ACC8(0, u0)
            ACC8(1, u1)
            ACC8(2, u2)
            ACC8(3, u3)
        }
        float inv = (n0 > 0) ? 1.0f / (float)n0 : 0.0f;
        short8 af[4];
#pragma unroll
        for (int kt = 0; kt < 4; ++kt) {
            short8 o;
#pragma unroll
            for (int j = 0; j < 8; ++j)
                o[j] = (short)__bfloat16_as_ushort(__float2bfloat16(a[kt][j] * inv));
            af[kt] = o;
        }

        // B-fragments straight from global (frag-linear, coalesced 1KB/wave reads)
#pragma unroll
        for (int kt = 0; kt < 4; ++kt) {
            short8 bf[8];
#pragma unroll
            for (int nt = 0; nt < 8; ++nt)
                bf[nt] = *reinterpret_cast<const short8*>(
                    wpu + ((size_t)(((p * 4 + kt) * 8 + nt) * 64 + lane)) * 8);
#pragma unroll
            for (int nt = 0; nt < 8; ++nt)
                acc[nt] = __builtin_amdgcn_mfma_f32_16x16x32_bf16(af[kt], bf[nt],
                                                                  acc[nt], 0, 0, 0);
        }

        b = nb;
        e = ne;
    }
#undef ACC8

    // epilogue: D row = 4*cg+i, col = nt*16+l16
    const int rbase = row0 + (cg << 2);
#pragma unroll
    for (int nt = 0; nt < 8; ++nt) {
        int col = nt * 16 + l16;
        float bv = bias[col];
#pragma unroll
        for (int i = 0; i < 4; ++i) {
            int r = rbase + i;
            if (r < n_nodes)
                out[(size_t)r * C128 + col] = acc[nt][i] + bv;
        }
    }
}

// ---------------- host ----------------

static inline char* align16p(char* p) {
    return (char*)(((uintptr_t)p + 15) & ~(uintptr_t)15);
}

extern "C" void kernel_launch(void* const* d_in, const int* in_sizes, int n_in,
                              void* d_out, int out_size, void* d_ws, size_t ws_size,
                              hipStream_t stream) {
    const float* x    = (const float*)d_in[0];
    const int*   ei   = (const int*)d_in[1];   // [2][E]
    const int*   et   = (const int*)d_in[2];   // [E]
    const float* W    = (const float*)d_in[3]; // [R][128][128]
    const float* bias = (const float*)d_in[4]; // [128]
    float* out = (float*)d_out;

    const int n_nodes = in_sizes[0] / C128;
    const int n_edges = in_sizes[2];
    const int n_rel   = in_sizes[3] / (C128 * C128);
    const int RN = n_rel * n_nodes;

    // workspace: off | cursor | part | rank | sorted_src | WbT | xb   (~21 MB)
    char* p = (char*)d_ws;
    unsigned* off = (unsigned*)p;      p += (size_t)(RN + 1) * 4; p = align16p(p);
    unsigned* cursor = (unsigned*)p;   p += (size_t)RN * 4;       p = align16p(p);
    unsigned* part = (unsigned*)p;     p += 4096 * 4;
    unsigned* rank = (unsigned*)p;     p += (size_t)n_edges * 4;  p = align16p(p);
    int* sorted_src = (int*)p;         p += (size_t)n_edges * 4;  p = align16p(p);
    __hip_bfloat16* WbT = (__hip_bfloat16*)p; p += (size_t)n_rel * C128 * C128 * 2; p = align16p(p);
    __hip_bfloat16* xb = (__hip_bfloat16*)p;

    hipMemsetAsync(cursor, 0, (size_t)RN * 4, stream);

    // hist(+rank, 4 edges/thread) + wconv + xconv in one launch
    int wtot = n_rel * C128 * C128;
    int xt8 = n_nodes * (C128 / 8);
    int hblk = (n_edges + 1023) / 1024;
    int wblk = (wtot + 255) / 256;
    int xblk = (xt8 + 255) / 256;
    pre_kernel<<<hblk + wblk + xblk, 256, 0, stream>>>(ei, et, cursor, rank, W, WbT, x, xb,
                                                       n_edges, n_nodes, hblk, wblk, wtot, xt8);

    int nblk = (RN + 1023) / 1024;
    scan1_kernel<<<nblk, 256, 0, stream>>>(cursor, part, RN);
    scan23_kernel<<<nblk, 256, 0, stream>>>(cursor, off, part, RN, n_edges);
    place_kernel<<<(n_edges + 1023) / 1024, 256, 0, stream>>>(ei, et, off, rank, sorted_src,
                                                              n_edges, n_nodes);

    int mblk = (n_nodes + BR - 1) / BR;
    fused_kernel<<<mblk, 64, 0, stream>>>(xb, sorted_src, off, WbT, bias, out,
                                          n_nodes, n_rel);
}